// Round 1
// baseline (90.370 us; speedup 1.0000x reference)
//
#include <hip/hip_runtime.h>
#include <stdint.h>

#define ROWS 8192     // B*N
#define D    128
#define CSPLIT 16
#define CPS  (ROWS / CSPLIT)   // 512 cols per split

typedef __bf16 bf16x8 __attribute__((ext_vector_type(8)));
typedef float  f32x4  __attribute__((ext_vector_type(4)));

__device__ __forceinline__ ushort f2bf(float f) {
    union { float f; uint32_t u; } x; x.f = f;
    uint32_t r = x.u + 0x7FFFu + ((x.u >> 16) & 1u);
    return (ushort)(r >> 16);
}

// ---- Kernel 1: L2-normalize rows of both inputs, cast to bf16 ----
__global__ __launch_bounds__(256) void k_norm(
    const float* __restrict__ fk, const float* __restrict__ fq,
    ushort* __restrict__ fkn, ushort* __restrict__ fqn)
{
    int gw = (blockIdx.x * 256 + threadIdx.x) >> 6;   // one wave per row
    int l  = threadIdx.x & 63;
    const float* src; ushort* dst; int r;
    if (gw < ROWS) { src = fk; dst = fkn; r = gw; }
    else           { src = fq; dst = fqn; r = gw - ROWS; }
    float2 v = *reinterpret_cast<const float2*>(&src[r * D + l * 2]);
    float ss = v.x * v.x + v.y * v.y;
    #pragma unroll
    for (int m = 1; m < 64; m <<= 1) ss += __shfl_xor(ss, m, 64);
    float inv = 1.0f / fmaxf(sqrtf(ss), 1e-12f);
    ushort2 o; o.x = f2bf(v.x * inv); o.y = f2bf(v.y * inv);
    *reinterpret_cast<ushort2*>(&dst[r * D + l * 2]) = o;
}

// ---- Kernel 2: fused Gram + exp + masked accumulation ----
// grid = (128 row-tiles, 16 col-splits), block = 256 (4 waves, 16 rows each)
__global__ __launch_bounds__(256) void k_gram(
    const ushort* __restrict__ fkn, const ushort* __restrict__ fqn,
    float* __restrict__ pneg, float* __restrict__ ppos)
{
    __shared__ ushort lds[2 * 64 * D];   // 32 KiB: [0..63]=fk tile, [64..127]=fq tile (swizzled)
    const int rt  = blockIdx.x;
    const int cs  = blockIdx.y;
    const int w   = threadIdx.x >> 6;
    const int l   = threadIdx.x & 63;
    const int lrow = l >> 4;             // 0..3
    const int lcol = l & 15;             // 0..15
    const int r0  = rt * 64;

    // stage 64 rows of a row-major [64][128] bf16 tile into LDS, XOR-swizzled 16B chunks
    auto stage = [&](const ushort* __restrict__ src, int base) {
        #pragma unroll
        for (int t = 0; t < 4; ++t) {
            int row = w * 16 + t * 4 + lrow;          // 0..63
            int4 v = *reinterpret_cast<const int4*>(src + row * D + lcol * 8);
            int slot = lcol ^ (row & 7);              // G4 swizzle: kills 32-way bank conflict
            *reinterpret_cast<int4*>(&lds[base + row * D + slot * 8]) = v;
        }
    };

    // ---- row tiles -> A fragments in registers ----
    stage(fkn + r0 * D, 0);
    stage(fqn + r0 * D, 64 * D);
    __syncthreads();

    bf16x8 ak[4], aq[4];
    {
        int arow = w * 16 + lcol;                     // A: m = lane&15
        #pragma unroll
        for (int ks = 0; ks < 4; ++ks) {              // k = ks*32 + 8*(lane>>4) + e
            int slot = (ks * 4 + lrow) ^ (arow & 7);
            ak[ks] = *reinterpret_cast<const bf16x8*>(&lds[arow * D + slot * 8]);
            aq[ks] = *reinterpret_cast<const bf16x8*>(&lds[64 * D + arow * D + slot * 8]);
        }
    }
    __syncthreads();

    float accp[4] = {0.f, 0.f, 0.f, 0.f};
    float accn[4] = {0.f, 0.f, 0.f, 0.f};

    for (int ct = 0; ct < CPS / 64; ++ct) {
        const int cbase = cs * CPS + ct * 64;
        stage(fkn + cbase * D, 0);
        stage(fqn + cbase * D, 64 * D);
        __syncthreads();
        const bool isDiag = (cbase == r0);            // whole 64-col tile is the m==i block
        #pragma unroll
        for (int cc = 0; cc < 4; ++cc) {              // 16-col chunks
            f32x4 sk = {0.f, 0.f, 0.f, 0.f}, sq = {0.f, 0.f, 0.f, 0.f};
            int brow = cc * 16 + lcol;                // B: n = lane&15 (Gram => B^T layout == row-major)
            #pragma unroll
            for (int ks = 0; ks < 4; ++ks) {
                int slot = (ks * 4 + lrow) ^ (brow & 7);
                bf16x8 bk = *reinterpret_cast<const bf16x8*>(&lds[brow * D + slot * 8]);
                bf16x8 bq = *reinterpret_cast<const bf16x8*>(&lds[64 * D + brow * D + slot * 8]);
                sk = __builtin_amdgcn_mfma_f32_16x16x32_bf16(ak[ks], bk, sk, 0, 0, 0);
                sq = __builtin_amdgcn_mfma_f32_16x16x32_bf16(aq[ks], bq, sq, 0, 0, 0);
            }
            // C layout (m89/m91): row = (lane>>4)*4 + e, col = lane&15
            if (isDiag) {
                #pragma unroll
                for (int e = 0; e < 4; ++e) accp[e] += __expf(sk[e]);
            } else {
                #pragma unroll
                for (int e = 0; e < 4; ++e) accn[e] += __expf(sk[e]) * sq[e];
            }
        }
        __syncthreads();
    }

    // reduce across the 16 lanes (low 4 lane bits) that share the same 4 output rows
    #pragma unroll
    for (int m = 1; m <= 8; m <<= 1) {
        #pragma unroll
        for (int e = 0; e < 4; ++e) {
            accp[e] += __shfl_xor(accp[e], m, 64);
            accn[e] += __shfl_xor(accn[e], m, 64);
        }
    }
    if (lcol == 0) {
        #pragma unroll
        for (int e = 0; e < 4; ++e) {
            int gr = r0 + w * 16 + lrow * 4 + e;
            ppos[cs * ROWS + gr] = accp[e];
            pneg[cs * ROWS + gr] = accn[e];
        }
    }
}

// ---- Kernel 3: combine partials, per-row loss, mean ----
__global__ __launch_bounds__(256) void k_loss(
    const float* __restrict__ pneg, const float* __restrict__ ppos,
    float* __restrict__ out)
{
    float s = 0.f;
    for (int r = threadIdx.x; r < ROWS; r += 256) {
        float pos = 0.f, neg = 0.f;
        #pragma unroll
        for (int p = 0; p < CSPLIT; ++p) { pos += ppos[p * ROWS + r]; neg += pneg[p * ROWS + r]; }
        s += log1pf(neg / pos);
    }
    #pragma unroll
    for (int m = 1; m < 64; m <<= 1) s += __shfl_xor(s, m, 64);
    __shared__ float red[4];
    if ((threadIdx.x & 63) == 0) red[threadIdx.x >> 6] = s;
    __syncthreads();
    if (threadIdx.x == 0) out[0] = (red[0] + red[1] + red[2] + red[3]) * (1.0f / ROWS);
}

extern "C" void kernel_launch(void* const* d_in, const int* in_sizes, int n_in,
                              void* d_out, int out_size, void* d_ws, size_t ws_size,
                              hipStream_t stream)
{
    const float* fk = (const float*)d_in[0];
    const float* fq = (const float*)d_in[1];
    ushort* fkn = (ushort*)d_ws;                       // 2 MB
    ushort* fqn = fkn + ROWS * D;                      // 2 MB
    float*  pneg = (float*)((char*)d_ws + 2u * ROWS * D * sizeof(ushort));  // 512 KB
    float*  ppos = pneg + CSPLIT * ROWS;               // 512 KB

    k_norm<<<(2 * ROWS) / 4, 256, 0, stream>>>(fk, fq, fkn, fqn);
    k_gram<<<dim3(ROWS / 64, CSPLIT), 256, 0, stream>>>(fkn, fqn, pneg, ppos);
    k_loss<<<1, 256, 0, stream>>>(pneg, ppos, (float*)d_out);
}

// Round 2
// 51.201 us; speedup vs baseline: 1.7650x; 1.7650x over previous
//
#include <hip/hip_runtime.h>
#include <stdint.h>

#define ROWS 8192     // B*N
#define D    128
#define CSPLIT 16
#define CPS  (ROWS / CSPLIT)    // 512 cols per split
#define BM   256
#define BN   64
#define NT   (CPS / BN)         // 8 col tiles per split

typedef __bf16 bf16x8 __attribute__((ext_vector_type(8)));
typedef float  f32x4  __attribute__((ext_vector_type(4)));

typedef const __attribute__((address_space(1))) uint32_t guint;
typedef __attribute__((address_space(3))) uint32_t luint;

__device__ __forceinline__ void gload_lds16(const void* g, void* l) {
    __builtin_amdgcn_global_load_lds((guint*)g, (luint*)l, 16, 0, 0);
}

__device__ __forceinline__ ushort f2bf(float f) {
    union { float f; uint32_t u; } x; x.f = f;
    uint32_t r = x.u + 0x7FFFu + ((x.u >> 16) & 1u);
    return (ushort)(r >> 16);
}

// ---- Kernel 1: L2-normalize rows of both inputs, cast to bf16 ----
__global__ __launch_bounds__(256) void k_norm(
    const float* __restrict__ fk, const float* __restrict__ fq,
    ushort* __restrict__ fkn, ushort* __restrict__ fqn)
{
    int gw = (blockIdx.x * 256 + threadIdx.x) >> 6;   // one wave per row
    int l  = threadIdx.x & 63;
    const float* src; ushort* dst; int r;
    if (gw < ROWS) { src = fk; dst = fkn; r = gw; }
    else           { src = fq; dst = fqn; r = gw - ROWS; }
    float2 v = *reinterpret_cast<const float2*>(&src[r * D + l * 2]);
    float ss = v.x * v.x + v.y * v.y;
    #pragma unroll
    for (int m = 1; m < 64; m <<= 1) ss += __shfl_xor(ss, m, 64);
    float inv = 1.0f / fmaxf(sqrtf(ss), 1e-12f);
    ushort2 o; o.x = f2bf(v.x * inv); o.y = f2bf(v.y * inv);
    *reinterpret_cast<ushort2*>(&dst[r * D + l * 2]) = o;
}

// ---- Kernel 2: fused Gram + exp + masked accumulation ----
// grid = (32 row-tiles, 16 col-splits) = 512 blocks (2/CU), block = 512 (8 waves x 32 rows)
__global__ __launch_bounds__(512, 4) void k_gram(
    const ushort* __restrict__ fkn, const ushort* __restrict__ fqn,
    float* __restrict__ pneg, float* __restrict__ ppos)
{
    __shared__ ushort lds[2][2 * BN * D];   // 2 bufs x (fk tile 16KB + fq tile 16KB) = 64 KiB
    const int rt = blockIdx.x;
    const int cs = blockIdx.y;
    const int w  = threadIdx.x >> 6;        // 0..7
    const int l  = threadIdx.x & 63;
    const int lrow = l >> 4, lcol = l & 15;
    const int r0 = rt * BM;

    // Pre-swizzled per-lane SOURCE byte offsets (rule #21: gload_lds writes linearly,
    // so apply the inverse swizzle on the global address; read side uses same XOR).
    // LDS chunk L = w*128 + i*64 + l  ->  row = L>>4, slot = L&15, src col = slot^(row&7)
    int off[2];
    #pragma unroll
    for (int i = 0; i < 2; ++i) {
        int L = w * 128 + i * 64 + l;
        int row = L >> 4, slot = L & 15;
        int col = slot ^ (row & 7);
        off[i] = row * 256 + col * 16;
    }

    // A fragments (2 row-groups x 4 k-steps, both tensors), direct global->reg, once.
    bf16x8 ak[2][4], aq[2][4];
    #pragma unroll
    for (int rg = 0; rg < 2; ++rg) {
        int arow = r0 + w * 32 + rg * 16 + lcol;      // A row: m = lane&15
        #pragma unroll
        for (int ks = 0; ks < 4; ++ks) {              // k = ks*32 + (lane>>4)*8 + e
            ak[rg][ks] = *reinterpret_cast<const bf16x8*>(fkn + arow * D + ks * 32 + lrow * 8);
            aq[rg][ks] = *reinterpret_cast<const bf16x8*>(fqn + arow * D + ks * 32 + lrow * 8);
        }
    }

    // this wave's 32 rows all lie in one i-block => diag col tile is wave-uniform
    const int diagc = ((r0 + w * 32) >> 6) << 6;

    auto issue_stage = [&](int buf, int cbase) {
        const char* fkb = (const char*)fkn + (size_t)cbase * 256;
        const char* fqb = (const char*)fqn + (size_t)cbase * 256;
        ushort* lk = &lds[buf][w * 1024];
        ushort* lq = &lds[buf][BN * D + w * 1024];
        gload_lds16(fkb + off[0], lk);
        gload_lds16(fkb + off[1], lk + 512);
        gload_lds16(fqb + off[0], lq);
        gload_lds16(fqb + off[1], lq + 512);
    };

    float accp[2][4] = {{0.f,0.f,0.f,0.f},{0.f,0.f,0.f,0.f}};
    float accn[2][4] = {{0.f,0.f,0.f,0.f},{0.f,0.f,0.f,0.f}};

    issue_stage(0, cs * CPS);
    __syncthreads();

    int cur = 0;
    for (int t = 0; t < NT; ++t) {
        const int cbase = cs * CPS + t * BN;
        if (t + 1 < NT) issue_stage(cur ^ 1, cbase + BN);   // prefetch next tile (async)
        const bool diag = (cbase == diagc);                 // wave-uniform branch
        const ushort* bkb = &lds[cur][0];
        const ushort* bqb = &lds[cur][BN * D];
        #pragma unroll
        for (int cc = 0; cc < 4; ++cc) {
            int brow = cc * 16 + lcol;                      // B row: n = lane&15
            f32x4 sk0 = {0,0,0,0}, sk1 = {0,0,0,0}, sq0 = {0,0,0,0}, sq1 = {0,0,0,0};
            #pragma unroll
            for (int ks = 0; ks < 4; ++ks) {
                int slot = (ks * 4 + lrow) ^ (brow & 7);
                bf16x8 bk = *reinterpret_cast<const bf16x8*>(bkb + brow * D + slot * 8);
                bf16x8 bq = *reinterpret_cast<const bf16x8*>(bqb + brow * D + slot * 8);
                sk0 = __builtin_amdgcn_mfma_f32_16x16x32_bf16(ak[0][ks], bk, sk0, 0, 0, 0);
                sk1 = __builtin_amdgcn_mfma_f32_16x16x32_bf16(ak[1][ks], bk, sk1, 0, 0, 0);
                sq0 = __builtin_amdgcn_mfma_f32_16x16x32_bf16(aq[0][ks], bq, sq0, 0, 0, 0);
                sq1 = __builtin_amdgcn_mfma_f32_16x16x32_bf16(aq[1][ks], bq, sq1, 0, 0, 0);
            }
            // C layout: row = (lane>>4)*4 + e, col = lane&15
            if (diag) {
                #pragma unroll
                for (int e = 0; e < 4; ++e) {
                    accp[0][e] += __expf(sk0[e]);
                    accp[1][e] += __expf(sk1[e]);
                }
            } else {
                #pragma unroll
                for (int e = 0; e < 4; ++e) {
                    accn[0][e] += __expf(sk0[e]) * sq0[e];
                    accn[1][e] += __expf(sk1[e]) * sq1[e];
                }
            }
        }
        __syncthreads();   // drains vmcnt (next tile staged) + lgkm (reads of cur done)
        cur ^= 1;
    }

    // reduce across the 16 lanes sharing the same output rows
    #pragma unroll
    for (int m = 1; m <= 8; m <<= 1) {
        #pragma unroll
        for (int rg = 0; rg < 2; ++rg)
            #pragma unroll
            for (int e = 0; e < 4; ++e) {
                accp[rg][e] += __shfl_xor(accp[rg][e], m, 64);
                accn[rg][e] += __shfl_xor(accn[rg][e], m, 64);
            }
    }
    if (lcol == 0) {
        #pragma unroll
        for (int rg = 0; rg < 2; ++rg)
            #pragma unroll
            for (int e = 0; e < 4; ++e) {
                int gr = r0 + w * 32 + rg * 16 + lrow * 4 + e;
                ppos[cs * ROWS + gr] = accp[rg][e];
                pneg[cs * ROWS + gr] = accn[rg][e];
            }
    }
}

// ---- Kernel 3a: per-row loss, 32-block partial sums ----
__global__ __launch_bounds__(256) void k_loss1(
    const float* __restrict__ pneg, const float* __restrict__ ppos,
    float* __restrict__ bsum)
{
    int r = blockIdx.x * 256 + threadIdx.x;
    float pos = 0.f, neg = 0.f;
    #pragma unroll
    for (int p = 0; p < CSPLIT; ++p) { pos += ppos[p * ROWS + r]; neg += pneg[p * ROWS + r]; }
    float s = log1pf(neg / pos);
    #pragma unroll
    for (int m = 1; m < 64; m <<= 1) s += __shfl_xor(s, m, 64);
    __shared__ float red[4];
    if ((threadIdx.x & 63) == 0) red[threadIdx.x >> 6] = s;
    __syncthreads();
    if (threadIdx.x == 0) bsum[blockIdx.x] = red[0] + red[1] + red[2] + red[3];
}

// ---- Kernel 3b: final mean ----
__global__ void k_loss2(const float* __restrict__ bsum, float* __restrict__ out)
{
    int l = threadIdx.x;
    float s = (l < 32) ? bsum[l] : 0.f;
    #pragma unroll
    for (int m = 1; m < 64; m <<= 1) s += __shfl_xor(s, m, 64);
    if (l == 0) out[0] = s * (1.0f / ROWS);
}

extern "C" void kernel_launch(void* const* d_in, const int* in_sizes, int n_in,
                              void* d_out, int out_size, void* d_ws, size_t ws_size,
                              hipStream_t stream)
{
    const float* fk = (const float*)d_in[0];
    const float* fq = (const float*)d_in[1];
    ushort* fkn = (ushort*)d_ws;                        // 2 MB
    ushort* fqn = fkn + ROWS * D;                       // 2 MB
    float*  pneg = (float*)(fqn + ROWS * D);            // 512 KB
    float*  ppos = pneg + CSPLIT * ROWS;                // 512 KB
    float*  bsum = ppos + CSPLIT * ROWS;                // 128 B

    k_norm<<<(2 * ROWS) / 4, 256, 0, stream>>>(fk, fq, fkn, fqn);
    k_gram<<<dim3(ROWS / BM, CSPLIT), 512, 0, stream>>>(fkn, fqn, pneg, ppos);
    k_loss1<<<32, 256, 0, stream>>>(pneg, ppos, bsum);
    k_loss2<<<1, 64, 0, stream>>>(bsum, (float*)d_out);
}